// Round 2
// baseline (42.306 us; speedup 1.0000x reference)
//
#include <hip/hip_runtime.h>

typedef __attribute__((ext_vector_type(4))) float  f32x4;
typedef __attribute__((ext_vector_type(8))) short  short8;
typedef __attribute__((ext_vector_type(2))) unsigned int u32x2;

#define NN 200          // N (neighbors / nodes per batch row)
#define EDIM 128
#define FDIM 16
#define AROW_STRIDE 40  // shorts per A-row in LDS (32 used + 8 pad)

__device__ __forceinline__ unsigned short f2bf(float f) {
    unsigned u = __float_as_uint(f);
    u += 0x7FFFu + ((u >> 16) & 1u);   // round-to-nearest-even
    return (unsigned short)(u >> 16);
}

__device__ __forceinline__ float tanh_fast(float x) {
    // tanh(x) = 1 - 2/(1+e^{2x});  e^{2x} = exp2(x * 2*log2(e))
    float e = __builtin_amdgcn_exp2f(x * 2.8853900817779268f);
    float r = __builtin_amdgcn_rcpf(1.0f + e);
    return __builtin_fmaf(-2.0f, r, 1.0f);
}

// One block per (b,n). Computes the ENTIRE op for that row:
//   hi[e]  = sum_e' h[e'] W_node[e,e']              (4 chained MFMAs, K=128)
//   agg[e] = mean_m tanh( hi[e] + sum_f ef[m,f] W_edge[e,f] + W[m] W_weight[e] )
//            (13 MFMAs, K=32 = 16 ef + 1 W + 15 zero, C-input = hiacc)
//   out[f] = sum_e agg[e] W_out[f,e] + b_out[f]     (f32 vector + LDS reduce)
__global__ __launch_bounds__(512) void fused_kernel(
    const float* __restrict__ h, const float* __restrict__ ef,
    const float* __restrict__ Wadj, const float* __restrict__ W_node,
    const float* __restrict__ W_edge, const float* __restrict__ W_weight,
    const float* __restrict__ W_out, const float* __restrict__ b_out,
    float* __restrict__ out)
{
    __shared__ short Abf[208 * AROW_STRIDE];   // 16640 B bf16 A-tile [m][k]
    __shared__ float agg_lds[EDIM];
    __shared__ float red[512];

    const int tid  = threadIdx.x;
    const int bn   = blockIdx.x;
    const int lane = tid & 63;
    const int wid  = tid >> 6;          // 8 waves = 8 e-tiles of 16
    const int g    = lane >> 4;         // k-group / row-group (0..3)
    const int l15  = lane & 15;
    const int e_b  = wid * 16 + l15;    // this lane's e column

    // ---- B fragment for the edge/weight projection (K=32 x N=16) ----
    // k<16: W_edge[e][k], k==16: W_weight[e], else 0
    short8 bfrag = {0, 0, 0, 0, 0, 0, 0, 0};
    if (g < 2) {
        const float* p = W_edge + e_b * FDIM + g * 8;
        f32x4 v0 = *(const f32x4*)(p);
        f32x4 v1 = *(const f32x4*)(p + 4);
        bfrag[0] = (short)f2bf(v0.x); bfrag[1] = (short)f2bf(v0.y);
        bfrag[2] = (short)f2bf(v0.z); bfrag[3] = (short)f2bf(v0.w);
        bfrag[4] = (short)f2bf(v1.x); bfrag[5] = (short)f2bf(v1.y);
        bfrag[6] = (short)f2bf(v1.z); bfrag[7] = (short)f2bf(v1.w);
    } else if (g == 2) {
        bfrag[0] = (short)f2bf(W_weight[e_b]);
    }

    // ---- h / W_node fragments for the hi projection (K=128 as 4x32) ----
    // A[r,k] = h[k] for all r (broadcast rows)  ->  D rows all equal hi[e]
    short8 ah[4], bn4[4];
    {
        const float* hrow = h + bn * EDIM;
        const float* wrow = W_node + e_b * EDIM;
#pragma unroll
        for (int s = 0; s < 4; ++s) {
            int k0 = s * 32 + g * 8;
            f32x4 a0 = *(const f32x4*)(hrow + k0);
            f32x4 a1 = *(const f32x4*)(hrow + k0 + 4);
            f32x4 w0 = *(const f32x4*)(wrow + k0);
            f32x4 w1 = *(const f32x4*)(wrow + k0 + 4);
            short8 av, wv;
            av[0]=(short)f2bf(a0.x); av[1]=(short)f2bf(a0.y);
            av[2]=(short)f2bf(a0.z); av[3]=(short)f2bf(a0.w);
            av[4]=(short)f2bf(a1.x); av[5]=(short)f2bf(a1.y);
            av[6]=(short)f2bf(a1.z); av[7]=(short)f2bf(a1.w);
            wv[0]=(short)f2bf(w0.x); wv[1]=(short)f2bf(w0.y);
            wv[2]=(short)f2bf(w0.z); wv[3]=(short)f2bf(w0.w);
            wv[4]=(short)f2bf(w1.x); wv[5]=(short)f2bf(w1.y);
            wv[6]=(short)f2bf(w1.z); wv[7]=(short)f2bf(w1.w);
            ah[s] = av; bn4[s] = wv;
        }
    }

    // ---- stage A tile: cols 0..15 = bf16(ef[m,:]) ----
    for (int idx = tid; idx < 800; idx += 512) {      // 800 f32x4 = 200 rows x 16
        int m  = idx >> 2;
        int k4 = (idx & 3) * 4;
        f32x4 v = *(const f32x4*)(ef + (size_t)bn * (NN * FDIM) + idx * 4);
        unsigned lo = (unsigned)f2bf(v.x) | ((unsigned)f2bf(v.y) << 16);
        unsigned hi2 = (unsigned)f2bf(v.z) | ((unsigned)f2bf(v.w) << 16);
        u32x2 pk = {lo, hi2};
        *(u32x2*)(Abf + m * AROW_STRIDE + k4) = pk;
    }
    // cols 16..31: W[m] at k=16, zeros elsewhere; pad rows 200..207 fully zero
    {
        const short8 z = {0,0,0,0,0,0,0,0};
        for (int m = tid; m < 208; m += 512) {
            short wv = (m < NN) ? (short)f2bf(Wadj[bn * NN + m]) : (short)0;
            short8 zw = {wv,0,0,0,0,0,0,0};
            *(short8*)(Abf + m * AROW_STRIDE + 16) = zw;  // cols 16..23
            *(short8*)(Abf + m * AROW_STRIDE + 24) = z;   // cols 24..31
            if (m >= NN) {
                *(short8*)(Abf + m * AROW_STRIDE)     = z; // cols 0..7
                *(short8*)(Abf + m * AROW_STRIDE + 8) = z; // cols 8..15
            }
        }
    }

    // ---- hi accumulator: 4 chained MFMAs (overlaps with staging waits) ----
    f32x4 hiacc = {0.0f, 0.0f, 0.0f, 0.0f};
#pragma unroll
    for (int s = 0; s < 4; ++s)
        hiacc = __builtin_amdgcn_mfma_f32_16x16x32_bf16(ah[s], bn4[s], hiacc, 0, 0, 0);

    __syncthreads();

    // ---- main loop: 13 m-tiles of 16 ----
    float part = 0.0f;
#pragma unroll
    for (int mt = 0; mt < 13; ++mt) {
        short8 a = *(const short8*)(Abf + (mt * 16 + l15) * AROW_STRIDE + g * 8);
        f32x4 cacc = __builtin_amdgcn_mfma_f32_16x16x32_bf16(a, bfrag, hiacc, 0, 0, 0);
        if (mt < 12 || g < 2) {   // mt==12: D rows 200..207 (g>=2) are pad
            part += tanh_fast(cacc[0]);
            part += tanh_fast(cacc[1]);
            part += tanh_fast(cacc[2]);
            part += tanh_fast(cacc[3]);
        }
    }
    // lanes l, l^16, l^32, l^48 share column e -> reduce row-groups
    part += __shfl_xor(part, 16);
    part += __shfl_xor(part, 32);

    if (lane < 16)
        agg_lds[wid * 16 + lane] = part * (1.0f / 200.0f);
    __syncthreads();

    // ---- out projection: out[f] = sum_e agg[e] W_out[f,e] + b_out[f] ----
    {
        const int f = tid & 127;
        const int c = tid >> 7;           // e-quarter 0..3
        const float* wrow = W_out + f * EDIM + c * 32;
        const float* arow = agg_lds + c * 32;
        float o = 0.0f;
#pragma unroll
        for (int j = 0; j < 32; j += 4) {
            f32x4 w4 = *(const f32x4*)(wrow + j);
            f32x4 a4 = *(const f32x4*)(arow + j);
            o = __builtin_fmaf(w4.x, a4.x, o);
            o = __builtin_fmaf(w4.y, a4.y, o);
            o = __builtin_fmaf(w4.z, a4.z, o);
            o = __builtin_fmaf(w4.w, a4.w, o);
        }
        red[tid] = o;
    }
    __syncthreads();
    if (tid < 128)
        out[bn * EDIM + tid] = red[tid] + red[tid + 128] + red[tid + 256]
                             + red[tid + 384] + b_out[tid];
}

extern "C" void kernel_launch(void* const* d_in, const int* in_sizes, int n_in,
                              void* d_out, int out_size, void* d_ws, size_t ws_size,
                              hipStream_t stream) {
    const float* h        = (const float*)d_in[0];
    const float* ef       = (const float*)d_in[1];
    const float* W        = (const float*)d_in[2];
    const float* W_node   = (const float*)d_in[3];
    const float* W_edge   = (const float*)d_in[4];
    const float* W_weight = (const float*)d_in[5];
    const float* W_out    = (const float*)d_in[6];
    const float* b_out    = (const float*)d_in[7];
    float* out = (float*)d_out;

    fused_kernel<<<1600, 512, 0, stream>>>(h, ef, W, W_node, W_edge, W_weight,
                                           W_out, b_out, out);
}